// Round 1
// 268.292 us; speedup vs baseline: 1.0615x; 1.0615x over previous
//
#include <hip/hip_runtime.h>
#include <stdint.h>

#define TOL 1e-2f
#define WPB 4
// ws layout: [0..128): 8 hashed flag slots (2 u64 each); [192..200): ctl {S, ok};
//            [4096..): z checkpoints, one 2 MB slab per step.
#define WS_CTL_OFF 192
#define WS_Z_OFF   4096

// Per-wave LDS (768 floats):
//   [0..511]   A rows, dense stride 16 (setup); slots 0..63 reused as p-buffer in loop
//   [512..767] G staging (16x16, dense) for uniform broadcasts
#define LDSW 768

__device__ __forceinline__ float bcastf(float v, int l) {
    return __int_as_float(__builtin_amdgcn_readlane(__float_as_int(v), l));
}

template <int PAT>
__device__ __forceinline__ float swz(float v) {
    return __int_as_float(__builtin_amdgcn_ds_swizzle(__float_as_int(v), PAT));
}
#define SWZ_XOR16 0x401F   // src = lane ^ 16

// MODE 0: run mi steps from z0; store z_k checkpoints; OR per-step (res>=TOL) bits
//         into hashed global flag slots.
// MODE 1: fallback replay (only if ctl[1]==0): run ctl[0] steps, write out.
template <int MODE>
__global__ __launch_bounds__(256) __attribute__((amdgpu_waves_per_eu(1)))
void dys_pass(
    const float* __restrict__ u_nom,     // (B,16)
    const float* __restrict__ Amat,      // (B,32,16)
    const float* __restrict__ bvec,      // (B,32)
    const int*   __restrict__ mi_ptr,
    const int*   __restrict__ ctl,       // {S, stored_ok}
    unsigned long long* __restrict__ flags,
    float*       __restrict__ zstore,
    int zcap,
    float*       __restrict__ out,
    int B)
{
    if (MODE == 1) { if (ctl[1]) return; }   // checkpoint path valid: gather handles out

    const int tid   = threadIdx.x;
    const int lane  = tid & 63;
    const int wib   = tid >> 6;
    const int elem  = blockIdx.x * WPB + wib;
    const int row32 = lane & 31;
    const int col16 = lane & 15;

    // Wave-PRIVATE LDS region. No __syncthreads() anywhere: all accesses are
    // same-wave, ordered by in-order DS completion (lgkmcnt).
    __shared__ __align__(16) float ldsT[WPB][LDSW];
    float* T = ldsT[wib];

    // ---- load A row (dup on upper half), u, b ----
    const float* Ab = Amat + (size_t)elem * 512 + (size_t)row32 * 16;
    float A_row[16];
    float4 a0, a1, a2, a3;
    {
        a0 = ((const float4*)Ab)[0];
        a1 = ((const float4*)Ab)[1];
        a2 = ((const float4*)Ab)[2];
        a3 = ((const float4*)Ab)[3];
        A_row[0]=a0.x;  A_row[1]=a0.y;  A_row[2]=a0.z;  A_row[3]=a0.w;
        A_row[4]=a1.x;  A_row[5]=a1.y;  A_row[6]=a1.z;  A_row[7]=a1.w;
        A_row[8]=a2.x;  A_row[9]=a2.y;  A_row[10]=a2.z; A_row[11]=a2.w;
        A_row[12]=a3.x; A_row[13]=a3.y; A_row[14]=a3.z; A_row[15]=a3.w;
    }
    if (lane < 32) {
        float4* Td = (float4*)(T + row32 * 16);
        Td[0] = a0; Td[1] = a1; Td[2] = a2; Td[3] = a3;
    }
    const float un = u_nom[(size_t)elem * 16 + col16];
    const float bv = bvec[(size_t)elem * 32 + row32];

    // ===================== Woodbury setup =====================
    // N = I + 2AA^T (32x32).  N^-1 = I - 2 A G A^T with G = (I + 2A^T A)^-1 (16x16).
    // Identities (G,H=A^T A commute):  QA = A G ;  AtQ = G A^T ;
    //   AtQA = H G = (I - G)/2 ;  Q = I - 2 (QA) A^T.
    // Final W layout per lane (same as verified kernel):
    //   lanes 0-31  (i = lane&15): [AtQA_i(16) | AtQ_i(32)]
    //   lanes 32-63 (j = lane-32): [QA_j(16)   | Q_j(32)  ]

    // ---- P = I + 2*A^T A, row col16 (all lanes, dup x4) ----
    float P[16];
    #pragma unroll
    for (int j = 0; j < 16; ++j) P[j] = (j == col16) ? 1.f : 0.f;
    #pragma unroll
    for (int m = 0; m < 32; ++m) {
        float am  = T[m * 16 + col16];        // A[m][i], per-lane (16-consec, bcast dup)
        float am2 = am + am;
        const float4* Rm = (const float4*)(T + m * 16);   // A row m, uniform bcast
        #pragma unroll
        for (int q = 0; q < 4; ++q) {
            float4 r = Rm[q];
            P[4*q+0] = fmaf(am2, r.x, P[4*q+0]);
            P[4*q+1] = fmaf(am2, r.y, P[4*q+1]);
            P[4*q+2] = fmaf(am2, r.z, P[4*q+2]);
            P[4*q+3] = fmaf(am2, r.w, P[4*q+3]);
        }
    }

    // ---- in-place Gauss-Jordan 16x16: P becomes G row col16 ----
    #pragma unroll
    for (int p = 0; p < 16; ++p) {
        float piv = bcastf(P[p], p);
        float d = __builtin_amdgcn_rcpf(piv);
        d = d * (2.f - piv * d);                // one Newton step
        float g = P[p] * d;
        g = (col16 == p) ? (1.f - d) : g;
        float negg = -g;
        #pragma unroll
        for (int j = 0; j < 16; ++j) {
            if (j == p) continue;
            float spj = bcastf(P[j], p);        // OLD pivot-row value
            P[j] = fmaf(negg, spj, P[j]);
        }
        P[p] = (col16 == p) ? d : negg;
    }

    // ---- stage G rows to LDS[512..767] for uniform broadcasts ----
    if (lane < 16) {
        float4* Gd = (float4*)(T + 512 + col16 * 16);
        Gd[0] = make_float4(P[0],  P[1],  P[2],  P[3]);
        Gd[1] = make_float4(P[4],  P[5],  P[6],  P[7]);
        Gd[2] = make_float4(P[8],  P[9],  P[10], P[11]);
        Gd[3] = make_float4(P[12], P[13], P[14], P[15]);
    }

    // ---- W[0..15] = QA row row32 = sum_t A_row[t] * G[t][:]  (all lanes) ----
    float W[48];
    #pragma unroll
    for (int k = 0; k < 16; ++k) W[k] = 0.f;
    #pragma unroll
    for (int t = 0; t < 16; ++t) {
        float at = A_row[t];
        const float4* Gt = (const float4*)(T + 512 + t * 16);  // uniform bcast
        #pragma unroll
        for (int q = 0; q < 4; ++q) {
            float4 r = Gt[q];
            W[4*q+0] = fmaf(at, r.x, W[4*q+0]);
            W[4*q+1] = fmaf(at, r.y, W[4*q+1]);
            W[4*q+2] = fmaf(at, r.z, W[4*q+2]);
            W[4*q+3] = fmaf(at, r.w, W[4*q+3]);
        }
    }

    // ---- v = fused-dot operand: lanes<32 -> G row i ; lanes>=32 -> QA row j ----
    float v[16];
    #pragma unroll
    for (int k = 0; k < 16; ++k) v[k] = (lane < 32) ? P[k] : W[k];

    // ---- lanes 0-31: W[0..15] = AtQA row i = (I - G)/2 (free!) ----
    if (lane < 32) {
        #pragma unroll
        for (int k = 0; k < 16; ++k)
            W[k] = fmaf(P[k], -0.5f, (k == col16) ? 0.5f : 0.f);
    }

    // ---- fused: W[16+m] = lanes<32: (G A^T)[i][m] ; lanes>=32: Q[j][m] ----
    {
        const bool low = (lane < 32);
        #pragma unroll
        for (int m = 0; m < 32; ++m) {
            const float4* Rm = (const float4*)(T + m * 16);   // A row m, uniform
            float c0 = 0.f, c1 = 0.f, c2 = 0.f, c3 = 0.f;
            #pragma unroll
            for (int q = 0; q < 4; ++q) {
                float4 r = Rm[q];
                c0 = fmaf(v[4*q+0], r.x, c0);
                c1 = fmaf(v[4*q+1], r.y, c1);
                c2 = fmaf(v[4*q+2], r.z, c2);
                c3 = fmaf(v[4*q+3], r.w, c3);
            }
            float c = (c0 + c1) + (c2 + c3);
            float dsel = (m == row32) ? 1.f : 0.f;
            float up = fmaf(-2.f, c, dsel);                   // Q[j][m]
            W[16 + m] = low ? c : up;
        }
    }

    // ---- fold c = (lanes<32 ? AtQ.b : Q.b) ----
    float cneg;
    {
        float c0 = 0.f, c1 = 0.f;
        #pragma unroll
        for (int m = 0; m < 32; m += 2) {
            c0 = fmaf(W[16 + m], bcastf(bv, m),     c0);
            c1 = fmaf(W[17 + m], bcastf(bv, m + 1), c1);
        }
        cneg = -(c0 + c1);
    }

    // ---- per-iteration constants ----
    const float sgn   = (lane >= 16 && lane < 32) ? 1.f : -1.f;
    const float sgn0  = (lane & 16) ? -1.f : 1.f;     // for ee on lanes 0-31
    const float nun   = -un;
    const float half0 = (lane < 32) ? 0.5f : 0.f;     // replaces lane<32 select on t
    // p-buffer slots: s[0..15]<-lanes 0-15; h[0..31]<-lanes 32-63 (slots 16-47);
    // lanes 16-31 dump into slots 48-63.
    const int pslot = (lane < 16) ? lane : ((lane < 32) ? (32 + lane) : (lane - 16));

    const int mi = *mi_ptr;
    const int nsteps = (MODE == 0) ? mi : ctl[0];

    // Checkpoint store: uniform SGPR base advanced per step + 32-bit lane offset.
    const uint32_t zoff = (uint32_t)elem * 64u + (uint32_t)lane;
    float* zbase = zstore;
    const size_t zstrideE = (size_t)B * 64;

    float z = 0.f;
    unsigned long long m0 = 0ull, m1 = 0ull, b0 = 1ull, b1 = 0ull;

    const float4* Pv = (const float4*)T;

    for (int k = 1; k <= nsteps; ++k) {
        float z16 = swz<SWZ_XOR16>(z);
        float x   = fmaxf(z, 0.f);
        float x16 = fmaxf(z16, 0.f);
        float t1  = x - x16;
        float s   = (t1 - (z - z16)) + un;          // lanes 0-15 valid
        float h   = fmaf(2.f, x, -z);               // lanes 32-63 valid

        T[pslot] = (lane < 32) ? s : h;             // 1 ds_write_b32, 2-way aliased
        float ee = fmaf(sgn0, t1, nun);             // e[lane&15] on lanes 0-31

        float acc0 = cneg, acc1 = 0.f, acc2 = 0.f, acc3 = 0.f;
        #pragma unroll
        for (int q = 0; q < 12; ++q) {
            float4 p = Pv[q];                       // uniform-address broadcast read
            acc0 = fmaf(W[4*q+0], p.x, acc0);
            acc1 = fmaf(W[4*q+1], p.y, acc1);
            acc2 = fmaf(W[4*q+2], p.z, acc2);
            acc3 = fmaf(W[4*q+3], p.w, acc3);
        }
        float acc = (acc0 + acc1) + (acc2 + acc3);  // lanes 0-31: At.w ; 32-63: w

        float t    = fmaf(half0, ee, acc);          // no select: half0 is 0 on 32-63
        float znew = fmaf(sgn, t, x);

        if (MODE == 0) {
            unsigned long long cy = b0 >> 63;
            b0 <<= 1; b1 = (b1 << 1) | cy;          // b = 1 << k (uniform, SALU)
            unsigned long long any = __ballot(fabsf(znew - z) >= TOL);
            if (any) { m0 |= b0; m1 |= b1; }
            if (k <= zcap) { zbase[zoff] = znew; zbase += zstrideE; }
        }
        z = znew;
    }

    if (MODE == 0) {
        if (lane == 0) {
            int slot = blockIdx.x & 7;
            atomicOr(flags + 2 * slot,     m0);
            atomicOr(flags + 2 * slot + 1, m1);
        }
    } else {
        float z16b = swz<SWZ_XOR16>(z);
        if (lane < 16) out[(size_t)elem * 16 + lane] = z - z16b;
        out[(size_t)B * 16 + (size_t)elem * 64 + lane] = z;
    }
}

// S = (first k in [1,mi) with global residual < TOL) + 1, else mi.
__global__ void dys_reduce(const int* __restrict__ mi_ptr,
                           const unsigned long long* __restrict__ flags,
                           int zcap, int* __restrict__ ctl)
{
    if (threadIdx.x != 0) return;
    unsigned long long m0 = 0ull, m1 = 0ull;
    for (int s = 0; s < 8; ++s) { m0 |= flags[2*s]; m1 |= flags[2*s+1]; }
    int mi = *mi_ptr;
    int S = mi;
    for (int k = 1; k < mi && k < 128; ++k) {
        unsigned long long bit = (k < 64) ? ((m0 >> k) & 1ull)
                                          : ((m1 >> (k - 64)) & 1ull);
        if (!bit) { S = k + 1; break; }
    }
    if (S < 1) S = 1;
    ctl[0] = S;
    ctl[1] = (S <= zcap) ? 1 : 0;
}

__global__ __launch_bounds__(256) void dys_gather(
    const int* __restrict__ ctl, const float* __restrict__ zstore,
    float* __restrict__ out, int B)
{
    if (!ctl[1]) return;
    int tid  = blockIdx.x * 256 + threadIdx.x;
    int lane = tid & 63;
    int elem = tid >> 6;
    int S = ctl[0];
    float z = zstore[(size_t)(S - 1) * B * 64 + (size_t)elem * 64 + lane];
    float z16 = swz<SWZ_XOR16>(z);
    if (lane < 16) out[(size_t)elem * 16 + lane] = z - z16;
    out[(size_t)B * 16 + (size_t)elem * 64 + lane] = z;
}

extern "C" void kernel_launch(void* const* d_in, const int* in_sizes, int n_in,
                              void* d_out, int out_size, void* d_ws, size_t ws_size,
                              hipStream_t stream) {
    (void)n_in; (void)out_size;
    const float* u_nom = (const float*)d_in[0];
    const float* Amat  = (const float*)d_in[1];
    const float* bvec  = (const float*)d_in[2];
    const int*   mi    = (const int*)d_in[3];

    const int B = in_sizes[0] / 16;                  // 8192

    unsigned long long* flags = (unsigned long long*)d_ws;
    int* ctl = (int*)((char*)d_ws + WS_CTL_OFF);
    float* zstore = (float*)((char*)d_ws + WS_Z_OFF);

    const size_t stepBytes = (size_t)B * 64 * sizeof(float);   // 2 MB
    int zcap = 0;
    if (ws_size > WS_Z_OFF + stepBytes)
        zcap = (int)((ws_size - WS_Z_OFF) / stepBytes);
    if (zcap > 127) zcap = 127;                      // masks cover k < 128

    hipMemsetAsync(d_ws, 0, 256, stream);            // flags + ctl

    const int blocks = B / WPB;
    dys_pass<0><<<blocks, 64 * WPB, 0, stream>>>(u_nom, Amat, bvec, mi, ctl,
                                                 flags, zstore, zcap, (float*)d_out, B);
    dys_reduce<<<1, 64, 0, stream>>>(mi, flags, zcap, ctl);
    // Fallback replay (early-exits when checkpoints cover S):
    dys_pass<1><<<blocks, 64 * WPB, 0, stream>>>(u_nom, Amat, bvec, mi, ctl,
                                                 flags, zstore, zcap, (float*)d_out, B);
    // Checkpoint gather (early-exits when fallback ran):
    dys_gather<<<B * 64 / 256, 256, 0, stream>>>(ctl, zstore, (float*)d_out, B);
}

// Round 2
// 254.363 us; speedup vs baseline: 1.1197x; 1.0548x over previous
//
#include <hip/hip_runtime.h>
#include <stdint.h>

#define TOL 1e-2f
#define WPB 4
// ws layout: [0..128): 8 hashed flag slots (2 u64 each); [192..200): ctl {S, ok};
//            [4096..): z checkpoints, one 2 MB slab per step.
#define WS_CTL_OFF 192
#define WS_Z_OFF   4096

// Per-wave LDS (768 floats), SETUP ONLY (main loop is LDS-free except 1 swizzle):
//   [0..511]   A rows, dense stride 16
//   [512..767] G staging (16x16, dense) for uniform broadcasts
#define LDSW 768

__device__ __forceinline__ float bcastf(float v, int l) {
    return __int_as_float(__builtin_amdgcn_readlane(__float_as_int(v), l));
}

template <int PAT>
__device__ __forceinline__ float swz(float v) {
    return __int_as_float(__builtin_amdgcn_ds_swizzle(__float_as_int(v), PAT));
}
#define SWZ_XOR16 0x401F   // src = lane ^ 16

// MODE 0: run mi steps from z0; store z_k checkpoints; OR per-step (res>=TOL) bits
//         into hashed global flag slots.
// MODE 1: fallback replay (only if ctl[1]==0): run ctl[0] steps, write out.
template <int MODE>
__global__ __launch_bounds__(256) __attribute__((amdgpu_waves_per_eu(1)))
void dys_pass(
    const float* __restrict__ u_nom,     // (B,16)
    const float* __restrict__ Amat,      // (B,32,16)
    const float* __restrict__ bvec,      // (B,32)
    const int*   __restrict__ mi_ptr,
    const int*   __restrict__ ctl,       // {S, stored_ok}
    unsigned long long* __restrict__ flags,
    float*       __restrict__ zstore,
    int zcap,
    float*       __restrict__ out,
    int B)
{
    if (MODE == 1) { if (ctl[1]) return; }   // checkpoint path valid: gather handles out

    const int tid   = threadIdx.x;
    const int lane  = tid & 63;
    const int wib   = tid >> 6;
    const int elem  = blockIdx.x * WPB + wib;
    const int row32 = lane & 31;
    const int col16 = lane & 15;

    // Wave-PRIVATE LDS region. No __syncthreads() anywhere: all accesses are
    // same-wave, ordered by in-order DS completion (lgkmcnt).
    __shared__ __align__(16) float ldsT[WPB][LDSW];
    float* T = ldsT[wib];

    // ---- load A row (dup on upper half), u, b ----
    const float* Ab = Amat + (size_t)elem * 512 + (size_t)row32 * 16;
    float A_row[16];
    float4 a0, a1, a2, a3;
    {
        a0 = ((const float4*)Ab)[0];
        a1 = ((const float4*)Ab)[1];
        a2 = ((const float4*)Ab)[2];
        a3 = ((const float4*)Ab)[3];
        A_row[0]=a0.x;  A_row[1]=a0.y;  A_row[2]=a0.z;  A_row[3]=a0.w;
        A_row[4]=a1.x;  A_row[5]=a1.y;  A_row[6]=a1.z;  A_row[7]=a1.w;
        A_row[8]=a2.x;  A_row[9]=a2.y;  A_row[10]=a2.z; A_row[11]=a2.w;
        A_row[12]=a3.x; A_row[13]=a3.y; A_row[14]=a3.z; A_row[15]=a3.w;
    }
    if (lane < 32) {
        float4* Td = (float4*)(T + row32 * 16);
        Td[0] = a0; Td[1] = a1; Td[2] = a2; Td[3] = a3;
    }
    const float un = u_nom[(size_t)elem * 16 + col16];
    const float bv = bvec[(size_t)elem * 32 + row32];

    // ===================== Woodbury setup =====================
    // N = I + 2AA^T (32x32).  N^-1 = I - 2 A G A^T with G = (I + 2A^T A)^-1 (16x16).
    // Identities (G,H=A^T A commute):  QA = A G ;  AtQ = G A^T ;
    //   AtQA = H G = (I - G)/2 ;  Q = I - 2 (QA) A^T.
    // Final W layout per lane:
    //   lanes 0-31  (i = lane&15): [AtQA_i(16) | AtQ_i(32)]
    //   lanes 32-63 (j = lane-32): [QA_j(16)   | Q_j(32)  ]

    // ---- P = I + 2*A^T A, row col16 (all lanes, dup x4) ----
    float P[16];
    #pragma unroll
    for (int j = 0; j < 16; ++j) P[j] = (j == col16) ? 1.f : 0.f;
    #pragma unroll
    for (int m = 0; m < 32; ++m) {
        float am  = T[m * 16 + col16];        // A[m][i], per-lane (16-consec, bcast dup)
        float am2 = am + am;
        const float4* Rm = (const float4*)(T + m * 16);   // A row m, uniform bcast
        #pragma unroll
        for (int q = 0; q < 4; ++q) {
            float4 r = Rm[q];
            P[4*q+0] = fmaf(am2, r.x, P[4*q+0]);
            P[4*q+1] = fmaf(am2, r.y, P[4*q+1]);
            P[4*q+2] = fmaf(am2, r.z, P[4*q+2]);
            P[4*q+3] = fmaf(am2, r.w, P[4*q+3]);
        }
    }

    // ---- in-place Gauss-Jordan 16x16: P becomes G row col16 ----
    #pragma unroll
    for (int p = 0; p < 16; ++p) {
        float piv = bcastf(P[p], p);
        float d = __builtin_amdgcn_rcpf(piv);
        d = d * (2.f - piv * d);                // one Newton step
        float g = P[p] * d;
        g = (col16 == p) ? (1.f - d) : g;
        float negg = -g;
        #pragma unroll
        for (int j = 0; j < 16; ++j) {
            if (j == p) continue;
            float spj = bcastf(P[j], p);        // OLD pivot-row value
            P[j] = fmaf(negg, spj, P[j]);
        }
        P[p] = (col16 == p) ? d : negg;
    }

    // ---- stage G rows to LDS[512..767] for uniform broadcasts ----
    if (lane < 16) {
        float4* Gd = (float4*)(T + 512 + col16 * 16);
        Gd[0] = make_float4(P[0],  P[1],  P[2],  P[3]);
        Gd[1] = make_float4(P[4],  P[5],  P[6],  P[7]);
        Gd[2] = make_float4(P[8],  P[9],  P[10], P[11]);
        Gd[3] = make_float4(P[12], P[13], P[14], P[15]);
    }

    // ---- W[0..15] = QA row row32 = sum_t A_row[t] * G[t][:]  (all lanes) ----
    float W[48];
    #pragma unroll
    for (int k = 0; k < 16; ++k) W[k] = 0.f;
    #pragma unroll
    for (int t = 0; t < 16; ++t) {
        float at = A_row[t];
        const float4* Gt = (const float4*)(T + 512 + t * 16);  // uniform bcast
        #pragma unroll
        for (int q = 0; q < 4; ++q) {
            float4 r = Gt[q];
            W[4*q+0] = fmaf(at, r.x, W[4*q+0]);
            W[4*q+1] = fmaf(at, r.y, W[4*q+1]);
            W[4*q+2] = fmaf(at, r.z, W[4*q+2]);
            W[4*q+3] = fmaf(at, r.w, W[4*q+3]);
        }
    }

    // ---- v = fused-dot operand: lanes<32 -> G row i ; lanes>=32 -> QA row j ----
    float v[16];
    #pragma unroll
    for (int k = 0; k < 16; ++k) v[k] = (lane < 32) ? P[k] : W[k];

    // ---- lanes 0-31: W[0..15] = AtQA row i = (I - G)/2 (free!) ----
    if (lane < 32) {
        #pragma unroll
        for (int k = 0; k < 16; ++k)
            W[k] = fmaf(P[k], -0.5f, (k == col16) ? 0.5f : 0.f);
    }

    // ---- fused: W[16+m] = lanes<32: (G A^T)[i][m] ; lanes>=32: Q[j][m] ----
    {
        const bool low = (lane < 32);
        #pragma unroll
        for (int m = 0; m < 32; ++m) {
            const float4* Rm = (const float4*)(T + m * 16);   // A row m, uniform
            float c0 = 0.f, c1 = 0.f, c2 = 0.f, c3 = 0.f;
            #pragma unroll
            for (int q = 0; q < 4; ++q) {
                float4 r = Rm[q];
                c0 = fmaf(v[4*q+0], r.x, c0);
                c1 = fmaf(v[4*q+1], r.y, c1);
                c2 = fmaf(v[4*q+2], r.z, c2);
                c3 = fmaf(v[4*q+3], r.w, c3);
            }
            float c = (c0 + c1) + (c2 + c3);
            float dsel = (m == row32) ? 1.f : 0.f;
            float up = fmaf(-2.f, c, dsel);                   // Q[j][m]
            W[16 + m] = low ? c : up;
        }
    }

    // ---- fold c = (lanes<32 ? AtQ.b : Q.b) ----
    float cneg;
    {
        float c0 = 0.f, c1 = 0.f;
        #pragma unroll
        for (int m = 0; m < 32; m += 2) {
            c0 = fmaf(W[16 + m], bcastf(bv, m),     c0);
            c1 = fmaf(W[17 + m], bcastf(bv, m + 1), c1);
        }
        cneg = -(c0 + c1);
    }

    // ---- per-iteration constants ----
    const float sgn   = (lane >= 16 && lane < 32) ? 1.f : -1.f;
    const float sgn0  = (lane & 16) ? -1.f : 1.f;     // for ee on lanes 0-31
    const float nun   = -un;
    const float half0 = (lane < 32) ? 0.5f : 0.f;     // replaces lane<32 select on t

    const int mi = *mi_ptr;
    const int nsteps = (MODE == 0) ? mi : ctl[0];

    // Checkpoint store: uniform SGPR base advanced per step + 32-bit lane offset.
    const uint32_t zoff = (uint32_t)elem * 64u + (uint32_t)lane;
    float* zbase = zstore;
    const size_t zstrideE = (size_t)B * 64;

    float z = 0.f;
    unsigned long long m0 = 0ull, m1 = 0ull, b0 = 1ull, b1 = 0ull;

    // Main loop: LDS-FREE p-broadcast. p-values live in known lanes:
    //   p[i]    = s from lane i      (i = 0..15)
    //   p[16+m] = h from lane 32+m   (m = 0..31)
    // v_readlane -> SGPR, consumed as the 1 allowed SGPR operand of v_fma.
    // acc0..3 association identical to the LDS version (index mod 4) -> bit-exact.
    for (int k = 1; k <= nsteps; ++k) {
        float z16 = swz<SWZ_XOR16>(z);              // the only DS op per iter
        float x   = fmaxf(z, 0.f);
        float x16 = fmaxf(z16, 0.f);
        float t1  = x - x16;
        float s   = (t1 - (z - z16)) + un;          // lanes 0-15 valid
        float h   = fmaf(2.f, x, -z);               // lanes 32-63 valid
        float ee  = fmaf(sgn0, t1, nun);            // e[lane&15] on lanes 0-31

        float acc0 = cneg, acc1 = 0.f, acc2 = 0.f, acc3 = 0.f;
        #pragma unroll
        for (int q = 0; q < 4; ++q) {
            acc0 = fmaf(W[4*q+0], bcastf(s, 4*q+0), acc0);
            acc1 = fmaf(W[4*q+1], bcastf(s, 4*q+1), acc1);
            acc2 = fmaf(W[4*q+2], bcastf(s, 4*q+2), acc2);
            acc3 = fmaf(W[4*q+3], bcastf(s, 4*q+3), acc3);
        }
        #pragma unroll
        for (int q = 0; q < 8; ++q) {
            acc0 = fmaf(W[16+4*q+0], bcastf(h, 32+4*q+0), acc0);
            acc1 = fmaf(W[16+4*q+1], bcastf(h, 32+4*q+1), acc1);
            acc2 = fmaf(W[16+4*q+2], bcastf(h, 32+4*q+2), acc2);
            acc3 = fmaf(W[16+4*q+3], bcastf(h, 32+4*q+3), acc3);
        }
        float acc = (acc0 + acc1) + (acc2 + acc3);  // lanes 0-31: At.w ; 32-63: w

        float t    = fmaf(half0, ee, acc);          // half0 is 0 on lanes 32-63
        float znew = fmaf(sgn, t, x);

        if (MODE == 0) {
            unsigned long long cy = b0 >> 63;
            b0 <<= 1; b1 = (b1 << 1) | cy;          // b = 1 << k (uniform, SALU)
            unsigned long long any = __ballot(fabsf(znew - z) >= TOL);
            if (any) { m0 |= b0; m1 |= b1; }
            if (k <= zcap) { zbase[zoff] = znew; zbase += zstrideE; }
        }
        z = znew;
    }

    if (MODE == 0) {
        if (lane == 0) {
            int slot = blockIdx.x & 7;
            atomicOr(flags + 2 * slot,     m0);
            atomicOr(flags + 2 * slot + 1, m1);
        }
    } else {
        float z16b = swz<SWZ_XOR16>(z);
        if (lane < 16) out[(size_t)elem * 16 + lane] = z - z16b;
        out[(size_t)B * 16 + (size_t)elem * 64 + lane] = z;
    }
}

// S = (first k in [1,mi) with global residual < TOL) + 1, else mi.
__global__ void dys_reduce(const int* __restrict__ mi_ptr,
                           const unsigned long long* __restrict__ flags,
                           int zcap, int* __restrict__ ctl)
{
    if (threadIdx.x != 0) return;
    unsigned long long m0 = 0ull, m1 = 0ull;
    for (int s = 0; s < 8; ++s) { m0 |= flags[2*s]; m1 |= flags[2*s+1]; }
    int mi = *mi_ptr;
    int S = mi;
    for (int k = 1; k < mi && k < 128; ++k) {
        unsigned long long bit = (k < 64) ? ((m0 >> k) & 1ull)
                                          : ((m1 >> (k - 64)) & 1ull);
        if (!bit) { S = k + 1; break; }
    }
    if (S < 1) S = 1;
    ctl[0] = S;
    ctl[1] = (S <= zcap) ? 1 : 0;
}

__global__ __launch_bounds__(256) void dys_gather(
    const int* __restrict__ ctl, const float* __restrict__ zstore,
    float* __restrict__ out, int B)
{
    if (!ctl[1]) return;
    int tid  = blockIdx.x * 256 + threadIdx.x;
    int lane = tid & 63;
    int elem = tid >> 6;
    int S = ctl[0];
    float z = zstore[(size_t)(S - 1) * B * 64 + (size_t)elem * 64 + lane];
    float z16 = swz<SWZ_XOR16>(z);
    if (lane < 16) out[(size_t)elem * 16 + lane] = z - z16;
    out[(size_t)B * 16 + (size_t)elem * 64 + lane] = z;
}

extern "C" void kernel_launch(void* const* d_in, const int* in_sizes, int n_in,
                              void* d_out, int out_size, void* d_ws, size_t ws_size,
                              hipStream_t stream) {
    (void)n_in; (void)out_size;
    const float* u_nom = (const float*)d_in[0];
    const float* Amat  = (const float*)d_in[1];
    const float* bvec  = (const float*)d_in[2];
    const int*   mi    = (const int*)d_in[3];

    const int B = in_sizes[0] / 16;                  // 8192

    unsigned long long* flags = (unsigned long long*)d_ws;
    int* ctl = (int*)((char*)d_ws + WS_CTL_OFF);
    float* zstore = (float*)((char*)d_ws + WS_Z_OFF);

    const size_t stepBytes = (size_t)B * 64 * sizeof(float);   // 2 MB
    int zcap = 0;
    if (ws_size > WS_Z_OFF + stepBytes)
        zcap = (int)((ws_size - WS_Z_OFF) / stepBytes);
    if (zcap > 127) zcap = 127;                      // masks cover k < 128

    hipMemsetAsync(d_ws, 0, 256, stream);            // flags + ctl

    const int blocks = B / WPB;
    dys_pass<0><<<blocks, 64 * WPB, 0, stream>>>(u_nom, Amat, bvec, mi, ctl,
                                                 flags, zstore, zcap, (float*)d_out, B);
    dys_reduce<<<1, 64, 0, stream>>>(mi, flags, zcap, ctl);
    // Fallback replay (early-exits when checkpoints cover S):
    dys_pass<1><<<blocks, 64 * WPB, 0, stream>>>(u_nom, Amat, bvec, mi, ctl,
                                                 flags, zstore, zcap, (float*)d_out, B);
    // Checkpoint gather (early-exits when fallback ran):
    dys_gather<<<B * 64 / 256, 256, 0, stream>>>(ctl, zstore, (float*)d_out, B);
}